// Round 10
// baseline (400.665 us; speedup 1.0000x reference)
//
#include <hip/hip_runtime.h>

#define NB 8
#define NT 2048
#define NC 2048
#define NH 128

typedef short s8v __attribute__((ext_vector_type(8)));   // 8 bf16 (4 VGPRs) — MFMA A/B frag
typedef short s4v __attribute__((ext_vector_type(4)));   // 4 bf16 (8 B)
typedef float f4  __attribute__((ext_vector_type(4)));   // 4 fp32 — MFMA C/D frag

static __device__ __forceinline__ unsigned short f2bf(float f) {
    union { float f; unsigned int u; } v; v.f = f;
    unsigned int x = v.u;
    return (unsigned short)((x + 0x7FFFu + ((x >> 16) & 1u)) >> 16);  // RNE
}

static __device__ __forceinline__ s8v pack8(f4 lo, f4 hi) {          // fp32x8 -> bf16x8 (trunc)
    union { f4 f; unsigned int u[4]; } L, H; L.f = lo; H.f = hi;
    union { s8v s; unsigned int u[4]; } A;
    A.u[0] = __builtin_amdgcn_perm(L.u[1], L.u[0], 0x07060302u);
    A.u[1] = __builtin_amdgcn_perm(L.u[3], L.u[2], 0x07060302u);
    A.u[2] = __builtin_amdgcn_perm(H.u[1], H.u[0], 0x07060302u);
    A.u[3] = __builtin_amdgcn_perm(H.u[3], H.u[2], 0x07060302u);
    return A.s;
}

// ---------------------------------------------------------------------------
// Kernel 0: transpose + cast W[k][n] (2048x128 fp32) -> FRAGMENT-PACKED bf16:
// wt[nb][kb][quad*16+l16][8elems]  (nb = mat*8 + n/16, kb = k/32).
// grid (32 k-tiles of 64, 3 mats), block 256.  [verified R3-R9]
// ---------------------------------------------------------------------------
__global__ __launch_bounds__(256) void wtrans_k(
    const float* __restrict__ Wk, const float* __restrict__ Wq,
    const float* __restrict__ Wv, unsigned short* __restrict__ wt)
{
    __shared__ float Ls[64][129];                       // +1 pad: conflict-free transpose
    const int mat = blockIdx.y;
    const float* W = (mat == 0) ? Wq : (mat == 1) ? Wk : Wv;
    const int k0 = blockIdx.x * 64;
    const int t  = threadIdx.x;

    #pragma unroll
    for (int j = 0; j < 8; ++j) {                       // load 64x128 fp32, coalesced f4
        int flat = j * 1024 + t * 4;
        int k = flat >> 7, n = flat & 127;
        f4 v = *reinterpret_cast<const f4*>(W + (size_t)(k0 + k) * NH + n);
        Ls[k][n] = v[0]; Ls[k][n + 1] = v[1]; Ls[k][n + 2] = v[2]; Ls[k][n + 3] = v[3];
    }
    __syncthreads();

    const int n = t >> 1, half = t & 1;                 // thread: col n, one 32-k block
    unsigned short tmp[32];
    #pragma unroll
    for (int kk = 0; kk < 32; ++kk) tmp[kk] = f2bf(Ls[half * 32 + kk][n]);

    const int nb  = mat * 8 + (n >> 4);                 // 0..23
    const int l16 = n & 15;
    const int kbi = blockIdx.x * 2 + half;              // 0..63
    unsigned short* dst = wt + ((size_t)nb * 64 + kbi) * 512;
    #pragma unroll
    for (int v = 0; v < 4; ++v)                         // lane (l16, quad=v) slot
        *reinterpret_cast<s8v*>(dst + (v * 16 + l16) * 8) = *reinterpret_cast<s8v*>(tmp + v * 8);
}

// ---------------------------------------------------------------------------
// Kernel 1: projection + RoPE, TLP-MAXIMIZED.
// R10: the R5-R9 ledger shows every structure lands 91-135 µs with all pipes
// idle at <=2-4 waves/SIMD: wave-level Little's law (one ~600cy load batch
// per ~60cy MFMA batch, no reg-prefetch ever held by the compiler). So: keep
// R9's no-LDS no-barrier packed-load stream but TRIPLE the resident waves:
// grid (512 row-tiles x 3 mats) = 1536 blocks of 256 thr, M=32, wave covers
// 32 cols (acc[2][2] -> ~64 VGPR) -> 6 blocks/CU = 24 waves/CU = 6/SIMD.
// Cost: x logically read 3x (L3-resident, 256MB L3 holds all of x);
// B traffic unchanged (768 MB L2 aggregate).
// Outputs MFMA-FRAGMENT-PACKED for attn_k (mapping verified R5/R7/R8/R9).
// ---------------------------------------------------------------------------
__global__ __launch_bounds__(256) void proj_rope(
    const float* __restrict__ x, const unsigned short* __restrict__ wt,
    unsigned short* __restrict__ qp, unsigned short* __restrict__ kp,
    unsigned short* __restrict__ vp)
{
    const int tid  = threadIdx.x;
    const int wave = tid >> 6;                           // n-wave (0..3), 32 cols each
    const int lane = tid & 63;
    const int quad = lane >> 4, l16 = lane & 15;
    const int M0  = blockIdx.x * 32;
    const int mat = blockIdx.y;                          // 0=Q 1=K 2=V (block-uniform)

    // A source: lane (l16,quad) covers rows M0+mi*16+l16, k = kb*32+quad*8..+7
    const float* xb[2];
    #pragma unroll
    for (int mi = 0; mi < 2; ++mi)
        xb[mi] = x + (size_t)(M0 + mi * 16 + l16) * NC + quad * 8;

    // B source: packed frags for this mat's cols [wave*32, wave*32+32)
    const unsigned short* bb[2];
    #pragma unroll
    for (int ni = 0; ni < 2; ++ni)
        bb[ni] = wt + ((size_t)(mat * 8 + wave * 2 + ni) * 64) * 512 + lane * 8;

    f4 acc[2][2];
    #pragma unroll
    for (int mi = 0; mi < 2; ++mi)
        #pragma unroll
        for (int ni = 0; ni < 2; ++ni)
            acc[mi][ni] = (f4){0.f, 0.f, 0.f, 0.f};

    #pragma unroll 4
    for (int kb = 0; kb < 64; ++kb) {
        s8v a[2];
        #pragma unroll
        for (int mi = 0; mi < 2; ++mi) {
            f4 L = *reinterpret_cast<const f4*>(xb[mi] + kb * 32);
            f4 H = *reinterpret_cast<const f4*>(xb[mi] + kb * 32 + 4);
            a[mi] = pack8(L, H);
        }
        #pragma unroll
        for (int ni = 0; ni < 2; ++ni) {
            s8v b = *reinterpret_cast<const s8v*>(bb[ni] + (size_t)kb * 512);
            acc[0][ni] = __builtin_amdgcn_mfma_f32_16x16x32_bf16(a[0], b, acc[0][ni], 0, 0, 0);
            acc[1][ni] = __builtin_amdgcn_mfma_f32_16x16x32_bf16(a[1], b, acc[1][ni], 0, 0, 0);
        }
    }

    // ---- epilogue: RoPE + fragment-packed stores (mapping verified R5-R9) ----
    const float cfreq = -0.10381025296f;  // -log2(10000)/128
    const int tb   = M0 >> 11;            // batch
    const int tl   = M0 & 2047;           // t of first row (multiple of 32)
    const int half = (tl >> 5) & 1;       // which 32-row half of the 64-row k/v tile
    unsigned short* qpB = qp + (size_t)tb * 262144;
    unsigned short* kpB = kp + (size_t)tb * 262144;
    unsigned short* vpB = vp + (size_t)tb * 262144;
    const int qt  = tl >> 5;              // q-tile (32 rows)
    const int kt0 = tl >> 6;              // k/v tile (64 rows)

    #pragma unroll
    for (int mi = 0; mi < 2; ++mi) {
        #pragma unroll
        for (int ni = 0; ni < 2; ++ni) {
            const int col = wave * 32 + ni * 16 + l16;      // 0..127 within this mat
            float vv[4];
            #pragma unroll
            for (int r = 0; r < 4; ++r) {
                const int t = tl + mi * 16 + quad * 4 + r;
                float v = acc[mi][ni][r];
                if (mat < 2) {
                    float other = __shfl_xor(v, 1, 64);
                    float freq  = exp2f(cfreq * (float)(col & ~1));
                    float ang   = (float)t * freq;
                    float sn = sinf(ang), cs = cosf(ang);
                    v = (col & 1) ? (other * sn + v * cs)
                                  : (v * cs - other * sn);
                }
                vv[r] = v;
            }
            if (mat == 0) {
                const int ks = col >> 5, qq = (col >> 3) & 3, e = col & 7;
                unsigned short* d = qpB + ((((size_t)qt * 2 + mi) * 4 + ks) * 64 + qq * 16 + quad * 4) * 8 + e;
                #pragma unroll
                for (int r = 0; r < 4; ++r) d[r * 8] = f2bf(vv[r]);
            } else if (mat == 1) {
                const int ks = col >> 5, qq = (col >> 3) & 3, e = col & 7;
                const int nt = half * 2 + mi;
                unsigned short* d = kpB + ((((size_t)kt0 * 4 + nt) * 4 + ks) * 64 + qq * 16 + quad * 4) * 8 + e;
                #pragma unroll
                for (int r = 0; r < 4; ++r) d[r * 8] = f2bf(vv[r]);
            } else {
                const int dt  = col >> 4;                    // l16v == l16
                const int ks2 = half;
                const int qv  = mi * 2 + (quad >> 1);
                const int e4  = (quad & 1) * 4;
                unsigned short* d = vpB + ((((size_t)kt0 * 2 + ks2) * 8 + dt) * 64 + qv * 16 + l16) * 8 + e4;
                s4v pk;
                #pragma unroll
                for (int r = 0; r < 4; ++r) pk[r] = (short)f2bf(vv[r]);
                *reinterpret_cast<s4v*>(d) = pk;
            }
        }
    }
}

// ---------------------------------------------------------------------------
// Kernel 2: flash attention (causal). 32 q-rows per wave (2 m-frags),
// split-KV stride 4 across the block's 4 waves, private online-softmax state,
// LDS merge at the end. grid = (64 q-tiles of 32, 8 batches), block 256.
// EXACT R5/R7/R8/R9 version. Q/K/V FRAGMENT-PACKED: all loads 1KB bursts.
// Softmax in log2 domain + T13 defer-max (THR=8). P XOR-swizzled.
// ---------------------------------------------------------------------------
__global__ __launch_bounds__(256, 2) void attn_k(
    const unsigned short* __restrict__ qp, const unsigned short* __restrict__ kp,
    const unsigned short* __restrict__ vp, float* __restrict__ out)
{
    __shared__ unsigned short P[4][32 * 64];   // 16 KB, per-wave, swizzled
    __shared__ float Os[4][32][64];            // 32 KB (one half of d per pass)
    __shared__ float Ms[4][32], Ls[4][32], Lt[32];

    const int wave = threadIdx.x >> 6;
    const int lane = threadIdx.x & 63;
    const int quad = lane >> 4, l16 = lane & 15;
    const int b     = blockIdx.y;
    const int qrow0 = blockIdx.x * 32;
    const int qt    = blockIdx.x;
    const unsigned short* Qp = qp + (size_t)b * 262144;
    const unsigned short* Kp = kp + (size_t)b * 262144;
    const unsigned short* Vp = vp + (size_t)b * 262144;

    s8v qf[2][4];
    #pragma unroll
    for (int mi = 0; mi < 2; ++mi)
        #pragma unroll
        for (int ks = 0; ks < 4; ++ks)
            qf[mi][ks] = *reinterpret_cast<const s8v*>(
                Qp + ((((size_t)qt * 2 + mi) * 4 + ks) * 64 + lane) * 8);

    float m[2][4], ls[2][4];
    f4 o[2][8];
    #pragma unroll
    for (int mi = 0; mi < 2; ++mi) {
        #pragma unroll
        for (int r = 0; r < 4; ++r) { m[mi][r] = -INFINITY; ls[mi][r] = 0.f; }
        #pragma unroll
        for (int dt = 0; dt < 8; ++dt) o[mi][dt] = (f4){0.f, 0.f, 0.f, 0.f};
    }

    const int nkt = (qrow0 >> 6) + 1;        // works for qrow0 = 0/32 mod 64
    const float scale2 = 0.1275166948f;      // (1/sqrt(128)) * log2(e)

    for (int kt = wave; kt < nkt; kt += 4) {
        const int kbase = kt * 64;
        const bool domask = (kt == nkt - 1);
        const unsigned short* Kt = Kp + (size_t)kt * 8192;   // [nt][ks][lane][8]
        const unsigned short* Vt = Vp + (size_t)kt * 8192;   // [ks2][dt][lane][8]

        // S = Q K^T
        f4 s[2][4];
        #pragma unroll
        for (int nt = 0; nt < 4; ++nt) {
            f4 a0 = (f4){0.f, 0.f, 0.f, 0.f}, a1 = a0;
            #pragma unroll
            for (int ks = 0; ks < 4; ++ks) {
                s8v kf = *reinterpret_cast<const s8v*>(Kt + (((nt * 4 + ks) * 64) + lane) * 8);
                a0 = __builtin_amdgcn_mfma_f32_16x16x32_bf16(qf[0][ks], kf, a0, 0, 0, 0);
                a1 = __builtin_amdgcn_mfma_f32_16x16x32_bf16(qf[1][ks], kf, a1, 0, 0, 0);
            }
            s[0][nt] = a0; s[1][nt] = a1;
        }

        // tile max (log2 domain)
        float tmx[2][4];
        #pragma unroll
        for (int mi = 0; mi < 2; ++mi) {
            #pragma unroll
            for (int r = 0; r < 4; ++r) {
                const int trow = qrow0 + mi * 16 + quad * 4 + r;
                #pragma unroll
                for (int nt = 0; nt < 4; ++nt) {
                    float sv = s[mi][nt][r] * scale2;
                    if (domask && (kbase + nt * 16 + l16 > trow)) sv = -INFINITY;
                    s[mi][nt][r] = sv;
                }
                float tm = fmaxf(fmaxf(s[mi][0][r], s[mi][1][r]),
                                 fmaxf(s[mi][2][r], s[mi][3][r]));
                #pragma unroll
                for (int off = 1; off < 16; off <<= 1)
                    tm = fmaxf(tm, __shfl_xor(tm, off, 64));
                tmx[mi][r] = tm;
            }
        }

        // defer-max: only rescale when some row's max grew by > 8 (log2 units)
        bool grow = false;
        #pragma unroll
        for (int mi = 0; mi < 2; ++mi)
            #pragma unroll
            for (int r = 0; r < 4; ++r)
                grow = grow || (tmx[mi][r] > m[mi][r] + 8.0f);
        if (__any(grow)) {
            #pragma unroll
            for (int mi = 0; mi < 2; ++mi)
                #pragma unroll
                for (int r = 0; r < 4; ++r) {
                    const float mn = fmaxf(m[mi][r], tmx[mi][r]);
                    const float alpha = exp2f(m[mi][r] - mn);
                    m[mi][r] = mn;
                    ls[mi][r] *= alpha;
                    #pragma unroll
                    for (int dt = 0; dt < 8; ++dt) o[mi][dt][r] *= alpha;
                }
        }

        // P = exp2(S - m); per-lane partial row sums
        #pragma unroll
        for (int mi = 0; mi < 2; ++mi)
            #pragma unroll
            for (int r = 0; r < 4; ++r) {
                float rs = 0.f;
                #pragma unroll
                for (int nt = 0; nt < 4; ++nt) {
                    float p = exp2f(s[mi][nt][r] - m[mi][r]);
                    s[mi][nt][r] = p;
                    rs += p;
                }
                ls[mi][r] += rs;
            }

        // P (C layout) -> LDS, XOR-swizzled: pos = chunk ^ (row&7), chunk=8 shorts
        #pragma unroll
        for (int mi = 0; mi < 2; ++mi)
            #pragma unroll
            for (int nt = 0; nt < 4; ++nt)
                #pragma unroll
                for (int r = 0; r < 4; ++r) {
                    const int prow = mi * 16 + quad * 4 + r;
                    const int swz  = ((nt * 2 + (l16 >> 3)) ^ (prow & 7)) * 8 + (l16 & 7);
                    P[wave][prow * 64 + swz] = f2bf(s[mi][nt][r]);
                }

        // O += P @ V
        #pragma unroll
        for (int ks2 = 0; ks2 < 2; ++ks2) {
            s8v pa[2];
            #pragma unroll
            for (int mi = 0; mi < 2; ++mi) {
                const int prow = mi * 16 + l16;                  // prow&7 == l16&7
                const int pp = ((ks2 * 4 + quad) ^ (l16 & 7));
                pa[mi] = *reinterpret_cast<const s8v*>(&P[wave][prow * 64 + pp * 8]);
            }
            #pragma unroll
            for (int dt = 0; dt < 8; ++dt) {
                s8v vf = *reinterpret_cast<const s8v*>(Vt + (((ks2 * 8 + dt) * 64) + lane) * 8);
                o[0][dt] = __builtin_amdgcn_mfma_f32_16x16x32_bf16(pa[0], vf, o[0][dt], 0, 0, 0);
                o[1][dt] = __builtin_amdgcn_mfma_f32_16x16x32_bf16(pa[1], vf, o[1][dt], 0, 0, 0);
            }
        }
    }

    // reduce per-lane lsum across the 16-lane row group
    #pragma unroll
    for (int mi = 0; mi < 2; ++mi)
        #pragma unroll
        for (int r = 0; r < 4; ++r) {
            float v = ls[mi][r];
            #pragma unroll
            for (int off = 1; off < 16; off <<= 1) v += __shfl_xor(v, off, 64);
            ls[mi][r] = v;
        }

    // ---- merge the 4 per-wave partials (m in log2 domain -> exp2) ----
    if (l16 == 0) {
        #pragma unroll
        for (int mi = 0; mi < 2; ++mi)
            #pragma unroll
            for (int r = 0; r < 4; ++r) {
                Ms[wave][mi * 16 + quad * 4 + r] = m[mi][r];
                Ls[wave][mi * 16 + quad * 4 + r] = ls[mi][r];
            }
    }
    __syncthreads();

    #pragma unroll
    for (int mi = 0; mi < 2; ++mi)
        #pragma unroll
        for (int r = 0; r < 4; ++r) {
            const int row = mi * 16 + quad * 4 + r;
            float M = fmaxf(fmaxf(Ms[0][row], Ms[1][row]), fmaxf(Ms[2][row], Ms[3][row]));
            float sc = exp2f(m[mi][r] - M);
            float lt = Ls[0][row] * exp2f(Ms[0][row] - M) + Ls[1][row] * exp2f(Ms[1][row] - M)
                     + Ls[2][row] * exp2f(Ms[2][row] - M) + Ls[3][row] * exp2f(Ms[3][row] - M);
            if (wave == 0 && l16 == 0) Lt[row] = lt;
            #pragma unroll
            for (int dt = 0; dt < 8; ++dt) o[mi][dt][r] *= sc;
        }

    const int rrow = threadIdx.x >> 3;          // 0..31
    const int cx   = (threadIdx.x & 7) * 8;     // 0..56
    #pragma unroll
    for (int h = 0; h < 2; ++h) {
        __syncthreads();
        #pragma unroll
        for (int mi = 0; mi < 2; ++mi)
            #pragma unroll
            for (int dtl = 0; dtl < 4; ++dtl)
                #pragma unroll
                for (int r = 0; r < 4; ++r)
                    Os[wave][mi * 16 + quad * 4 + r][dtl * 16 + l16] = o[mi][h * 4 + dtl][r];
        __syncthreads();
        f4 s0 = (f4){0.f, 0.f, 0.f, 0.f}, s1 = s0;
        #pragma unroll
        for (int w = 0; w < 4; ++w) {
            s0 += *reinterpret_cast<const f4*>(&Os[w][rrow][cx]);
            s1 += *reinterpret_cast<const f4*>(&Os[w][rrow][cx + 4]);
        }
        const float rl = 1.0f / Lt[rrow];
        float* dst = &out[((size_t)b * NT + qrow0 + rrow) * NH + h * 64 + cx];
        *reinterpret_cast<f4*>(dst)     = s0 * rl;
        *reinterpret_cast<f4*>(dst + 4) = s1 * rl;
    }
}

// ---------------------------------------------------------------------------
extern "C" void kernel_launch(void* const* d_in, const int* in_sizes, int n_in,
                              void* d_out, int out_size, void* d_ws, size_t ws_size,
                              hipStream_t stream) {
    const float* x  = (const float*)d_in[0];
    const float* Wk = (const float*)d_in[1];
    const float* Wq = (const float*)d_in[2];
    const float* Wv = (const float*)d_in[3];
    unsigned short* ws   = (unsigned short*)d_ws;
    unsigned short* wt   = ws;                      // 24 nb x 64 kb x 512 (packed W frags)
    unsigned short* qws  = ws  + 786432;            // 8 b x 64 qt x 2 x 4 x 64 x 8 (packed Q)
    unsigned short* kws  = qws + 2097152;           // 8 b x 32 kt x 4 x 4 x 64 x 8 (packed K)
    unsigned short* vtws = kws + 2097152;           // 8 b x 32 kt x 2 x 8 x 64 x 8 (packed V^T)
    float* outp = (float*)d_out;

    wtrans_k<<<dim3(32, 3), 256, 0, stream>>>(Wk, Wq, Wv, wt);
    proj_rope<<<dim3(512, 3), 256, 0, stream>>>(x, wt, qws, kws, vtws);
    attn_k<<<dim3(64, 8), 256, 0, stream>>>(qws, kws, vtws, outp);
}

// Round 11
// 317.109 us; speedup vs baseline: 1.2635x; 1.2635x over previous
//
#include <hip/hip_runtime.h>

#define NB 8
#define NT 2048
#define NC 2048
#define NH 128

typedef short s8v __attribute__((ext_vector_type(8)));   // 8 bf16 (4 VGPRs) — MFMA A/B frag
typedef short s4v __attribute__((ext_vector_type(4)));   // 4 bf16 (8 B)
typedef float f4  __attribute__((ext_vector_type(4)));   // 4 fp32 — MFMA C/D frag

static __device__ __forceinline__ unsigned short f2bf(float f) {
    union { float f; unsigned int u; } v; v.f = f;
    unsigned int x = v.u;
    return (unsigned short)((x + 0x7FFFu + ((x >> 16) & 1u)) >> 16);  // RNE
}

static __device__ __forceinline__ s8v pack8(f4 lo, f4 hi) {          // fp32x8 -> bf16x8 (trunc)
    union { f4 f; unsigned int u[4]; } L, H; L.f = lo; H.f = hi;
    union { s8v s; unsigned int u[4]; } A;
    A.u[0] = __builtin_amdgcn_perm(L.u[1], L.u[0], 0x07060302u);
    A.u[1] = __builtin_amdgcn_perm(L.u[3], L.u[2], 0x07060302u);
    A.u[2] = __builtin_amdgcn_perm(H.u[1], H.u[0], 0x07060302u);
    A.u[3] = __builtin_amdgcn_perm(H.u[3], H.u[2], 0x07060302u);
    return A.s;
}

// ---------------------------------------------------------------------------
// Kernel 0: transpose + cast W[k][n] (2048x128 fp32) -> FRAGMENT-PACKED bf16:
// wt[nb][kb][quad*16+l16][8elems]  (nb = mat*8 + n/16, kb = k/32).
// grid (32 k-tiles of 64, 3 mats), block 256.  [verified R3-R10]
// ---------------------------------------------------------------------------
__global__ __launch_bounds__(256) void wtrans_k(
    const float* __restrict__ Wk, const float* __restrict__ Wq,
    const float* __restrict__ Wv, unsigned short* __restrict__ wt)
{
    __shared__ float Ls[64][129];                       // +1 pad: conflict-free transpose
    const int mat = blockIdx.y;
    const float* W = (mat == 0) ? Wq : (mat == 1) ? Wk : Wv;
    const int k0 = blockIdx.x * 64;
    const int t  = threadIdx.x;

    #pragma unroll
    for (int j = 0; j < 8; ++j) {                       // load 64x128 fp32, coalesced f4
        int flat = j * 1024 + t * 4;
        int k = flat >> 7, n = flat & 127;
        f4 v = *reinterpret_cast<const f4*>(W + (size_t)(k0 + k) * NH + n);
        Ls[k][n] = v[0]; Ls[k][n + 1] = v[1]; Ls[k][n + 2] = v[2]; Ls[k][n + 3] = v[3];
    }
    __syncthreads();

    const int n = t >> 1, half = t & 1;                 // thread: col n, one 32-k block
    unsigned short tmp[32];
    #pragma unroll
    for (int kk = 0; kk < 32; ++kk) tmp[kk] = f2bf(Ls[half * 32 + kk][n]);

    const int nb  = mat * 8 + (n >> 4);                 // 0..23
    const int l16 = n & 15;
    const int kbi = blockIdx.x * 2 + half;              // 0..63
    unsigned short* dst = wt + ((size_t)nb * 64 + kbi) * 512;
    #pragma unroll
    for (int v = 0; v < 4; ++v)                         // lane (l16, quad=v) slot
        *reinterpret_cast<s8v*>(dst + (v * 16 + l16) * 8) = *reinterpret_cast<s8v*>(tmp + v * 8);
}

// ---------------------------------------------------------------------------
// Kernel 1: FUSED projection (Q,K,V in one pass over x) + RoPE.
// EXACT R5 version — measured best (91 µs) across the R5-R10 structure sweep
// (staged/16w/2blk/gl2lds-T3/no-barrier/max-TLP all 91-215 µs; the 2-phase
// structural overhead, m233, binds them all). block 512 (8 waves: 2m x 4n),
// M-tile 64, grid 256. A: global->reg (2 tiles early) -> pack bf16 ->
// ds_write; LDS dbuf 2 x 64rows x 144B. B: direct global->reg from
// fragment-packed wt. Outputs MFMA-FRAGMENT-PACKED for attn_k.
// ---------------------------------------------------------------------------
__global__ __launch_bounds__(512) void proj_rope(
    const float* __restrict__ x, const unsigned short* __restrict__ wt,
    unsigned short* __restrict__ qp, unsigned short* __restrict__ kp,
    unsigned short* __restrict__ vp)
{
    __shared__ char ALDS[2][9216];                       // 64 rows x 144B, dbuf

    const int tid  = threadIdx.x;
    const int wave = tid >> 6;
    const int lane = tid & 63;
    const int quad = lane >> 4, l16 = lane & 15;
    const int wm = wave >> 2, wn = wave & 3;             // 2m x 4n wave grid
    const int M0 = blockIdx.x * 64;

    // staging role: thread covers row srow (0..63), k-chunk sc (8 floats)
    const int srow = tid >> 3, sc = tid & 7;
    const float* xsrc = x + (size_t)(M0 + srow) * NC + sc * 8;
    char* sd0 = &ALDS[0][srow * 144 + sc * 16];
    char* sd1 = &ALDS[1][srow * 144 + sc * 16];

    const unsigned short* wtb = wt + (size_t)(wn * 6) * 32768 + lane * 8;

    f4 acc[2][6];
    #pragma unroll
    for (int mi = 0; mi < 2; ++mi)
        #pragma unroll
        for (int ni = 0; ni < 6; ++ni)
            acc[mi][ni] = (f4){0.f, 0.f, 0.f, 0.f};

    s8v bcur[2][6], bnxt[2][6];

    // prologue: x tiles 0,1 -> reg pairs; B tile 0 -> bcur; write tile0 -> buf0
    f4 a0lo = *reinterpret_cast<const f4*>(xsrc);
    f4 a0hi = *reinterpret_cast<const f4*>(xsrc + 4);
    f4 a1lo = *reinterpret_cast<const f4*>(xsrc + 64);
    f4 a1hi = *reinterpret_cast<const f4*>(xsrc + 68);
    #pragma unroll
    for (int ks = 0; ks < 2; ++ks)
        #pragma unroll
        for (int ni = 0; ni < 6; ++ni)
            bcur[ks][ni] = *reinterpret_cast<const s8v*>(wtb + (size_t)ni * 32768 + (size_t)ks * 512);
    *reinterpret_cast<s8v*>(sd0) = pack8(a0lo, a0hi);
    a0lo = *reinterpret_cast<const f4*>(xsrc + 128);     // tile 2
    a0hi = *reinterpret_cast<const f4*>(xsrc + 132);
    __syncthreads();

    for (int tt = 0; tt < 16; ++tt) {
        // ======== even phase: compute tile 2tt from buf0 with bcur ========
        *reinterpret_cast<s8v*>(sd1) = pack8(a1lo, a1hi);           // tile 2tt+1 -> buf1
        if (tt < 15) {                                               // x tile 2tt+3 -> pair1
            a1lo = *reinterpret_cast<const f4*>(xsrc + (size_t)(2 * tt + 3) * 64);
            a1hi = *reinterpret_cast<const f4*>(xsrc + (size_t)(2 * tt + 3) * 64 + 4);
        }
        #pragma unroll
        for (int ks = 0; ks < 2; ++ks)                               // B tile 2tt+1 -> bnxt
            #pragma unroll
            for (int ni = 0; ni < 6; ++ni)
                bnxt[ks][ni] = *reinterpret_cast<const s8v*>(
                    wtb + (size_t)ni * 32768 + (size_t)((2 * tt + 1) * 2 + ks) * 512);
        #pragma unroll
        for (int ksub = 0; ksub < 2; ++ksub) {
            const char* cur = ALDS[0];
            s8v a0 = *reinterpret_cast<const s8v*>(cur + (wm * 32 + l16) * 144 + (ksub * 4 + quad) * 16);
            s8v a1 = *reinterpret_cast<const s8v*>(cur + (wm * 32 + 16 + l16) * 144 + (ksub * 4 + quad) * 16);
            #pragma unroll
            for (int ni = 0; ni < 6; ++ni) {
                acc[0][ni] = __builtin_amdgcn_mfma_f32_16x16x32_bf16(a0, bcur[ksub][ni], acc[0][ni], 0, 0, 0);
                acc[1][ni] = __builtin_amdgcn_mfma_f32_16x16x32_bf16(a1, bcur[ksub][ni], acc[1][ni], 0, 0, 0);
            }
        }
        __syncthreads();

        // ======== odd phase: compute tile 2tt+1 from buf1 with bnxt ========
        if (tt < 15) {
            *reinterpret_cast<s8v*>(sd0) = pack8(a0lo, a0hi);        // tile 2tt+2 -> buf0
            if (tt < 14) {                                           // x tile 2tt+4 -> pair0
                a0lo = *reinterpret_cast<const f4*>(xsrc + (size_t)(2 * tt + 4) * 64);
                a0hi = *reinterpret_cast<const f4*>(xsrc + (size_t)(2 * tt + 4) * 64 + 4);
            }
            #pragma unroll
            for (int ks = 0; ks < 2; ++ks)                           // B tile 2tt+2 -> bcur
                #pragma unroll
                for (int ni = 0; ni < 6; ++ni)
                    bcur[ks][ni] = *reinterpret_cast<const s8v*>(
                        wtb + (size_t)ni * 32768 + (size_t)((2 * tt + 2) * 2 + ks) * 512);
        }
        #pragma unroll
        for (int ksub = 0; ksub < 2; ++ksub) {
            const char* cur = ALDS[1];
            s8v a0 = *reinterpret_cast<const s8v*>(cur + (wm * 32 + l16) * 144 + (ksub * 4 + quad) * 16);
            s8v a1 = *reinterpret_cast<const s8v*>(cur + (wm * 32 + 16 + l16) * 144 + (ksub * 4 + quad) * 16);
            #pragma unroll
            for (int ni = 0; ni < 6; ++ni) {
                acc[0][ni] = __builtin_amdgcn_mfma_f32_16x16x32_bf16(a0, bnxt[ksub][ni], acc[0][ni], 0, 0, 0);
                acc[1][ni] = __builtin_amdgcn_mfma_f32_16x16x32_bf16(a1, bnxt[ksub][ni], acc[1][ni], 0, 0, 0);
            }
        }
        __syncthreads();
    }

    // ---- epilogue: RoPE + fragment-packed stores ----
    const float cfreq = -0.10381025296f;  // -log2(10000)/128
    const int tb  = M0 >> 11;             // batch
    const int tl  = M0 & 2047;            // t of first row (multiple of 64)
    unsigned short* qpB = qp + (size_t)tb * 262144;
    unsigned short* kpB = kp + (size_t)tb * 262144;
    unsigned short* vpB = vp + (size_t)tb * 262144;
    const int qt0 = (tl >> 5) + wm;       // q-tile (32 rows)
    const int kt0 = tl >> 6;              // k/v tile (64 rows)

    #pragma unroll
    for (int mi = 0; mi < 2; ++mi) {
        #pragma unroll
        for (int ni = 0; ni < 6; ++ni) {
            const int outcol = wn * 96 + ni * 16 + l16;     // 0..383
            const int mat = outcol >> 7;                    // uniform per (wn,ni)
            const int col = outcol & 127;
            float vv[4];
            #pragma unroll
            for (int r = 0; r < 4; ++r) {
                const int t = tl + wm * 32 + mi * 16 + quad * 4 + r;
                float v = acc[mi][ni][r];
                if (mat < 2) {
                    float other = __shfl_xor(v, 1, 64);
                    float freq  = exp2f(cfreq * (float)(col & ~1));
                    float ang   = (float)t * freq;
                    float sn = sinf(ang), cs = cosf(ang);
                    v = (col & 1) ? (other * sn + v * cs)
                                  : (v * cs - other * sn);
                }
                vv[r] = v;
            }
            if (mat == 0) {
                const int ks = col >> 5, qq = (col >> 3) & 3, e = col & 7;
                unsigned short* d = qpB + ((((size_t)qt0 * 2 + mi) * 4 + ks) * 64 + qq * 16 + quad * 4) * 8 + e;
                #pragma unroll
                for (int r = 0; r < 4; ++r) d[r * 8] = f2bf(vv[r]);
            } else if (mat == 1) {
                const int ks = col >> 5, qq = (col >> 3) & 3, e = col & 7;
                const int nt = wm * 2 + mi;
                unsigned short* d = kpB + ((((size_t)kt0 * 4 + nt) * 4 + ks) * 64 + qq * 16 + quad * 4) * 8 + e;
                #pragma unroll
                for (int r = 0; r < 4; ++r) d[r * 8] = f2bf(vv[r]);
            } else {
                const int dt  = col >> 4;                    // l16v == l16
                const int ks2 = wm;
                const int qv  = mi * 2 + (quad >> 1);
                const int e4  = (quad & 1) * 4;
                unsigned short* d = vpB + ((((size_t)kt0 * 2 + ks2) * 8 + dt) * 64 + qv * 16 + l16) * 8 + e4;
                s4v pk;
                #pragma unroll
                for (int r = 0; r < 4; ++r) pk[r] = (short)f2bf(vv[r]);
                *reinterpret_cast<s4v*>(d) = pk;
            }
        }
    }
}

// ---------------------------------------------------------------------------
// Kernel 2: flash attention (causal). 32 q-rows per wave (2 m-frags),
// split-KV stride 4 across the block's 4 waves, private online-softmax state,
// LDS merge at the end. grid = (64 q-tiles of 32, 8 batches), block 256.
// R11: P (loop-only) and Os (post-loop-only) UNIONED -> LDS 49KB -> 34KB,
// with NO VGPR-capping launch bound (R6's (256,4) forced VGPR=64 -> spill;
// union itself verified correct there). LDS now allows up to 4 blocks/CU;
// expected limiter VGPR ~3 blocks/CU = 12 waves (1.5x TLP, zero-barrier loop).
// Q/K/V FRAGMENT-PACKED: every global load a single coalesced 1KB burst.
// Softmax in log2 domain + T13 defer-max (THR=8). P XOR-swizzled.
// ---------------------------------------------------------------------------
__global__ __launch_bounds__(256) void attn_k(
    const unsigned short* __restrict__ qp, const unsigned short* __restrict__ kp,
    const unsigned short* __restrict__ vp, float* __restrict__ out)
{
    __shared__ __align__(16) char SMEM[33920];
    auto* P  = reinterpret_cast<unsigned short(*)[2048]>(SMEM);   // [4][2048] 16KB (loop)
    auto* Os = reinterpret_cast<float(*)[32][64]>(SMEM);          // [4][32][64] 32KB (epilogue)
    float* MsF = reinterpret_cast<float*>(SMEM + 32768);          // [4][32]
    float* LsF = reinterpret_cast<float*>(SMEM + 33280);          // [4][32]
    float* Lt  = reinterpret_cast<float*>(SMEM + 33792);          // [32]

    const int wave = threadIdx.x >> 6;
    const int lane = threadIdx.x & 63;
    const int quad = lane >> 4, l16 = lane & 15;
    const int b     = blockIdx.y;
    const int qrow0 = blockIdx.x * 32;
    const int qt    = blockIdx.x;
    const unsigned short* Qp = qp + (size_t)b * 262144;
    const unsigned short* Kp = kp + (size_t)b * 262144;
    const unsigned short* Vp = vp + (size_t)b * 262144;

    s8v qf[2][4];
    #pragma unroll
    for (int mi = 0; mi < 2; ++mi)
        #pragma unroll
        for (int ks = 0; ks < 4; ++ks)
            qf[mi][ks] = *reinterpret_cast<const s8v*>(
                Qp + ((((size_t)qt * 2 + mi) * 4 + ks) * 64 + lane) * 8);

    float m[2][4], ls[2][4];
    f4 o[2][8];
    #pragma unroll
    for (int mi = 0; mi < 2; ++mi) {
        #pragma unroll
        for (int r = 0; r < 4; ++r) { m[mi][r] = -INFINITY; ls[mi][r] = 0.f; }
        #pragma unroll
        for (int dt = 0; dt < 8; ++dt) o[mi][dt] = (f4){0.f, 0.f, 0.f, 0.f};
    }

    const int nkt = (qrow0 >> 6) + 1;        // works for qrow0 = 0/32 mod 64
    const float scale2 = 0.1275166948f;      // (1/sqrt(128)) * log2(e)

    for (int kt = wave; kt < nkt; kt += 4) {
        const int kbase = kt * 64;
        const bool domask = (kt == nkt - 1);
        const unsigned short* Kt = Kp + (size_t)kt * 8192;   // [nt][ks][lane][8]
        const unsigned short* Vt = Vp + (size_t)kt * 8192;   // [ks2][dt][lane][8]

        // S = Q K^T
        f4 s[2][4];
        #pragma unroll
        for (int nt = 0; nt < 4; ++nt) {
            f4 a0 = (f4){0.f, 0.f, 0.f, 0.f}, a1 = a0;
            #pragma unroll
            for (int ks = 0; ks < 4; ++ks) {
                s8v kf = *reinterpret_cast<const s8v*>(Kt + (((nt * 4 + ks) * 64) + lane) * 8);
                a0 = __builtin_amdgcn_mfma_f32_16x16x32_bf16(qf[0][ks], kf, a0, 0, 0, 0);
                a1 = __builtin_amdgcn_mfma_f32_16x16x32_bf16(qf[1][ks], kf, a1, 0, 0, 0);
            }
            s[0][nt] = a0; s[1][nt] = a1;
        }

        // tile max (log2 domain)
        float tmx[2][4];
        #pragma unroll
        for (int mi = 0; mi < 2; ++mi) {
            #pragma unroll
            for (int r = 0; r < 4; ++r) {
                const int trow = qrow0 + mi * 16 + quad * 4 + r;
                #pragma unroll
                for (int nt = 0; nt < 4; ++nt) {
                    float sv = s[mi][nt][r] * scale2;
                    if (domask && (kbase + nt * 16 + l16 > trow)) sv = -INFINITY;
                    s[mi][nt][r] = sv;
                }
                float tm = fmaxf(fmaxf(s[mi][0][r], s[mi][1][r]),
                                 fmaxf(s[mi][2][r], s[mi][3][r]));
                #pragma unroll
                for (int off = 1; off < 16; off <<= 1)
                    tm = fmaxf(tm, __shfl_xor(tm, off, 64));
                tmx[mi][r] = tm;
            }
        }

        // defer-max: only rescale when some row's max grew by > 8 (log2 units)
        bool grow = false;
        #pragma unroll
        for (int mi = 0; mi < 2; ++mi)
            #pragma unroll
            for (int r = 0; r < 4; ++r)
                grow = grow || (tmx[mi][r] > m[mi][r] + 8.0f);
        if (__any(grow)) {
            #pragma unroll
            for (int mi = 0; mi < 2; ++mi)
                #pragma unroll
                for (int r = 0; r < 4; ++r) {
                    const float mn = fmaxf(m[mi][r], tmx[mi][r]);
                    const float alpha = exp2f(m[mi][r] - mn);
                    m[mi][r] = mn;
                    ls[mi][r] *= alpha;
                    #pragma unroll
                    for (int dt = 0; dt < 8; ++dt) o[mi][dt][r] *= alpha;
                }
        }

        // P = exp2(S - m); per-lane partial row sums
        #pragma unroll
        for (int mi = 0; mi < 2; ++mi)
            #pragma unroll
            for (int r = 0; r < 4; ++r) {
                float rs = 0.f;
                #pragma unroll
                for (int nt = 0; nt < 4; ++nt) {
                    float p = exp2f(s[mi][nt][r] - m[mi][r]);
                    s[mi][nt][r] = p;
                    rs += p;
                }
                ls[mi][r] += rs;
            }

        // P (C layout) -> LDS, XOR-swizzled: pos = chunk ^ (row&7), chunk=8 shorts
        #pragma unroll
        for (int mi = 0; mi < 2; ++mi)
            #pragma unroll
            for (int nt = 0; nt < 4; ++nt)
                #pragma unroll
                for (int r = 0; r < 4; ++r) {
                    const int prow = mi * 16 + quad * 4 + r;
                    const int swz  = ((nt * 2 + (l16 >> 3)) ^ (prow & 7)) * 8 + (l16 & 7);
                    P[wave][prow * 64 + swz] = f2bf(s[mi][nt][r]);
                }

        // O += P @ V
        #pragma unroll
        for (int ks2 = 0; ks2 < 2; ++ks2) {
            s8v pa[2];
            #pragma unroll
            for (int mi = 0; mi < 2; ++mi) {
                const int prow = mi * 16 + l16;                  // prow&7 == l16&7
                const int pp = ((ks2 * 4 + quad) ^ (l16 & 7));
                pa[mi] = *reinterpret_cast<const s8v*>(&P[wave][prow * 64 + pp * 8]);
            }
            #pragma unroll
            for (int dt = 0; dt < 8; ++dt) {
                s8v vf = *reinterpret_cast<const s8v*>(Vt + (((ks2 * 8 + dt) * 64) + lane) * 8);
                o[0][dt] = __builtin_amdgcn_mfma_f32_16x16x32_bf16(pa[0], vf, o[0][dt], 0, 0, 0);
                o[1][dt] = __builtin_amdgcn_mfma_f32_16x16x32_bf16(pa[1], vf, o[1][dt], 0, 0, 0);
            }
        }
    }

    // reduce per-lane lsum across the 16-lane row group
    #pragma unroll
    for (int mi = 0; mi < 2; ++mi)
        #pragma unroll
        for (int r = 0; r < 4; ++r) {
            float v = ls[mi][r];
            #pragma unroll
            for (int off = 1; off < 16; off <<= 1) v += __shfl_xor(v, off, 64);
            ls[mi][r] = v;
        }

    // ---- merge the 4 per-wave partials (m in log2 domain -> exp2) ----
    if (l16 == 0) {
        #pragma unroll
        for (int mi = 0; mi < 2; ++mi)
            #pragma unroll
            for (int r = 0; r < 4; ++r) {
                MsF[wave * 32 + mi * 16 + quad * 4 + r] = m[mi][r];
                LsF[wave * 32 + mi * 16 + quad * 4 + r] = ls[mi][r];
            }
    }
    __syncthreads();   // all waves done with kt loop => done with P (safe to reuse as Os)

    #pragma unroll
    for (int mi = 0; mi < 2; ++mi)
        #pragma unroll
        for (int r = 0; r < 4; ++r) {
            const int row = mi * 16 + quad * 4 + r;
            float M = fmaxf(fmaxf(MsF[row], MsF[32 + row]), fmaxf(MsF[64 + row], MsF[96 + row]));
            float sc = exp2f(m[mi][r] - M);
            float lt = LsF[row] * exp2f(MsF[row] - M) + LsF[32 + row] * exp2f(MsF[32 + row] - M)
                     + LsF[64 + row] * exp2f(MsF[64 + row] - M) + LsF[96 + row] * exp2f(MsF[96 + row] - M);
            if (wave == 0 && l16 == 0) Lt[row] = lt;
            #pragma unroll
            for (int dt = 0; dt < 8; ++dt) o[mi][dt][r] *= sc;
        }

    const int rrow = threadIdx.x >> 3;          // 0..31
    const int cx   = (threadIdx.x & 7) * 8;     // 0..56
    #pragma unroll
    for (int h = 0; h < 2; ++h) {
        __syncthreads();
        #pragma unroll
        for (int mi = 0; mi < 2; ++mi)
            #pragma unroll
            for (int dtl = 0; dtl < 4; ++dtl)
                #pragma unroll
                for (int r = 0; r < 4; ++r)
                    Os[wave][mi * 16 + quad * 4 + r][dtl * 16 + l16] = o[mi][h * 4 + dtl][r];
        __syncthreads();
        f4 s0 = (f4){0.f, 0.f, 0.f, 0.f}, s1 = s0;
        #pragma unroll
        for (int w = 0; w < 4; ++w) {
            s0 += *reinterpret_cast<const f4*>(&Os[w][rrow][cx]);
            s1 += *reinterpret_cast<const f4*>(&Os[w][rrow][cx + 4]);
        }
        const float rl = 1.0f / Lt[rrow];
        float* dst = &out[((size_t)b * NT + qrow0 + rrow) * NH + h * 64 + cx];
        *reinterpret_cast<f4*>(dst)     = s0 * rl;
        *reinterpret_cast<f4*>(dst + 4) = s1 * rl;
    }
}

// ---------------------------------------------------------------------------
extern "C" void kernel_launch(void* const* d_in, const int* in_sizes, int n_in,
                              void* d_out, int out_size, void* d_ws, size_t ws_size,
                              hipStream_t stream) {
    const float* x  = (const float*)d_in[0];
    const float* Wk = (const float*)d_in[1];
    const float* Wq = (const float*)d_in[2];
    const float* Wv = (const float*)d_in[3];
    unsigned short* ws   = (unsigned short*)d_ws;
    unsigned short* wt   = ws;                      // 24 nb x 64 kb x 512 (packed W frags)
    unsigned short* qws  = ws  + 786432;            // 8 b x 64 qt x 2 x 4 x 64 x 8 (packed Q)
    unsigned short* kws  = qws + 2097152;           // 8 b x 32 kt x 4 x 4 x 64 x 8 (packed K)
    unsigned short* vtws = kws + 2097152;           // 8 b x 32 kt x 2 x 8 x 64 x 8 (packed V^T)
    float* outp = (float*)d_out;

    wtrans_k<<<dim3(32, 3), 256, 0, stream>>>(Wk, Wq, Wv, wt);
    proj_rope<<<dim3(256), 512, 0, stream>>>(x, wt, qws, kws, vtws);
    attn_k<<<dim3(64, 8), 256, 0, stream>>>(qws, kws, vtws, outp);
}

// Round 12
// 280.759 us; speedup vs baseline: 1.4271x; 1.1295x over previous
//
#include <hip/hip_runtime.h>

#define NB 8
#define NT 2048
#define NC 2048
#define NH 128

typedef short s8v __attribute__((ext_vector_type(8)));   // 8 bf16 (4 VGPRs) — MFMA A/B frag
typedef short s4v __attribute__((ext_vector_type(4)));   // 4 bf16 (8 B)
typedef float f4  __attribute__((ext_vector_type(4)));   // 4 fp32 — MFMA C/D frag

static __device__ __forceinline__ unsigned short f2bf(float f) {
    union { float f; unsigned int u; } v; v.f = f;
    unsigned int x = v.u;
    return (unsigned short)((x + 0x7FFFu + ((x >> 16) & 1u)) >> 16);  // RNE
}

static __device__ __forceinline__ s8v pack8(f4 lo, f4 hi) {          // fp32x8 -> bf16x8 (trunc)
    union { f4 f; unsigned int u[4]; } L, H; L.f = lo; H.f = hi;
    union { s8v s; unsigned int u[4]; } A;
    A.u[0] = __builtin_amdgcn_perm(L.u[1], L.u[0], 0x07060302u);
    A.u[1] = __builtin_amdgcn_perm(L.u[3], L.u[2], 0x07060302u);
    A.u[2] = __builtin_amdgcn_perm(H.u[1], H.u[0], 0x07060302u);
    A.u[3] = __builtin_amdgcn_perm(H.u[3], H.u[2], 0x07060302u);
    return A.s;
}

// ---------------------------------------------------------------------------
// Kernel 0: transpose + cast W[k][n] (2048x128 fp32) -> FRAGMENT-PACKED bf16:
// wt[nb][kb][quad*16+l16][8elems]  (nb = mat*8 + n/16, kb = k/32).
// grid (32 k-tiles of 64, 3 mats), block 256.  [verified R3-R11]
// ---------------------------------------------------------------------------
__global__ __launch_bounds__(256) void wtrans_k(
    const float* __restrict__ Wk, const float* __restrict__ Wq,
    const float* __restrict__ Wv, unsigned short* __restrict__ wt)
{
    __shared__ float Ls[64][129];                       // +1 pad: conflict-free transpose
    const int mat = blockIdx.y;
    const float* W = (mat == 0) ? Wq : (mat == 1) ? Wk : Wv;
    const int k0 = blockIdx.x * 64;
    const int t  = threadIdx.x;

    #pragma unroll
    for (int j = 0; j < 8; ++j) {                       // load 64x128 fp32, coalesced f4
        int flat = j * 1024 + t * 4;
        int k = flat >> 7, n = flat & 127;
        f4 v = *reinterpret_cast<const f4*>(W + (size_t)(k0 + k) * NH + n);
        Ls[k][n] = v[0]; Ls[k][n + 1] = v[1]; Ls[k][n + 2] = v[2]; Ls[k][n + 3] = v[3];
    }
    __syncthreads();

    const int n = t >> 1, half = t & 1;                 // thread: col n, one 32-k block
    unsigned short tmp[32];
    #pragma unroll
    for (int kk = 0; kk < 32; ++kk) tmp[kk] = f2bf(Ls[half * 32 + kk][n]);

    const int nb  = mat * 8 + (n >> 4);                 // 0..23
    const int l16 = n & 15;
    const int kbi = blockIdx.x * 2 + half;              // 0..63
    unsigned short* dst = wt + ((size_t)nb * 64 + kbi) * 512;
    #pragma unroll
    for (int v = 0; v < 4; ++v)                         // lane (l16, quad=v) slot
        *reinterpret_cast<s8v*>(dst + (v * 16 + l16) * 8) = *reinterpret_cast<s8v*>(tmp + v * 8);
}

// ---------------------------------------------------------------------------
// Kernel 1: FUSED projection (Q,K,V in one pass over x) + RoPE.
// EXACT R5 version — measured best (91 µs) across the R5-R10 structure sweep.
// block 512 (8 waves: 2m x 4n), M-tile 64, grid 256. A: global->reg (2 tiles
// early) -> pack bf16 -> ds_write; LDS dbuf 2 x 64rows x 144B. B: direct
// global->reg from fragment-packed wt. Outputs MFMA-FRAGMENT-PACKED.
// ---------------------------------------------------------------------------
__global__ __launch_bounds__(512) void proj_rope(
    const float* __restrict__ x, const unsigned short* __restrict__ wt,
    unsigned short* __restrict__ qp, unsigned short* __restrict__ kp,
    unsigned short* __restrict__ vp)
{
    __shared__ char ALDS[2][9216];                       // 64 rows x 144B, dbuf

    const int tid  = threadIdx.x;
    const int wave = tid >> 6;
    const int lane = tid & 63;
    const int quad = lane >> 4, l16 = lane & 15;
    const int wm = wave >> 2, wn = wave & 3;             // 2m x 4n wave grid
    const int M0 = blockIdx.x * 64;

    // staging role: thread covers row srow (0..63), k-chunk sc (8 floats)
    const int srow = tid >> 3, sc = tid & 7;
    const float* xsrc = x + (size_t)(M0 + srow) * NC + sc * 8;
    char* sd0 = &ALDS[0][srow * 144 + sc * 16];
    char* sd1 = &ALDS[1][srow * 144 + sc * 16];

    const unsigned short* wtb = wt + (size_t)(wn * 6) * 32768 + lane * 8;

    f4 acc[2][6];
    #pragma unroll
    for (int mi = 0; mi < 2; ++mi)
        #pragma unroll
        for (int ni = 0; ni < 6; ++ni)
            acc[mi][ni] = (f4){0.f, 0.f, 0.f, 0.f};

    s8v bcur[2][6], bnxt[2][6];

    // prologue: x tiles 0,1 -> reg pairs; B tile 0 -> bcur; write tile0 -> buf0
    f4 a0lo = *reinterpret_cast<const f4*>(xsrc);
    f4 a0hi = *reinterpret_cast<const f4*>(xsrc + 4);
    f4 a1lo = *reinterpret_cast<const f4*>(xsrc + 64);
    f4 a1hi = *reinterpret_cast<const f4*>(xsrc + 68);
    #pragma unroll
    for (int ks = 0; ks < 2; ++ks)
        #pragma unroll
        for (int ni = 0; ni < 6; ++ni)
            bcur[ks][ni] = *reinterpret_cast<const s8v*>(wtb + (size_t)ni * 32768 + (size_t)ks * 512);
    *reinterpret_cast<s8v*>(sd0) = pack8(a0lo, a0hi);
    a0lo = *reinterpret_cast<const f4*>(xsrc + 128);     // tile 2
    a0hi = *reinterpret_cast<const f4*>(xsrc + 132);
    __syncthreads();

    for (int tt = 0; tt < 16; ++tt) {
        // ======== even phase: compute tile 2tt from buf0 with bcur ========
        *reinterpret_cast<s8v*>(sd1) = pack8(a1lo, a1hi);           // tile 2tt+1 -> buf1
        if (tt < 15) {                                               // x tile 2tt+3 -> pair1
            a1lo = *reinterpret_cast<const f4*>(xsrc + (size_t)(2 * tt + 3) * 64);
            a1hi = *reinterpret_cast<const f4*>(xsrc + (size_t)(2 * tt + 3) * 64 + 4);
        }
        #pragma unroll
        for (int ks = 0; ks < 2; ++ks)                               // B tile 2tt+1 -> bnxt
            #pragma unroll
            for (int ni = 0; ni < 6; ++ni)
                bnxt[ks][ni] = *reinterpret_cast<const s8v*>(
                    wtb + (size_t)ni * 32768 + (size_t)((2 * tt + 1) * 2 + ks) * 512);
        #pragma unroll
        for (int ksub = 0; ksub < 2; ++ksub) {
            const char* cur = ALDS[0];
            s8v a0 = *reinterpret_cast<const s8v*>(cur + (wm * 32 + l16) * 144 + (ksub * 4 + quad) * 16);
            s8v a1 = *reinterpret_cast<const s8v*>(cur + (wm * 32 + 16 + l16) * 144 + (ksub * 4 + quad) * 16);
            #pragma unroll
            for (int ni = 0; ni < 6; ++ni) {
                acc[0][ni] = __builtin_amdgcn_mfma_f32_16x16x32_bf16(a0, bcur[ksub][ni], acc[0][ni], 0, 0, 0);
                acc[1][ni] = __builtin_amdgcn_mfma_f32_16x16x32_bf16(a1, bcur[ksub][ni], acc[1][ni], 0, 0, 0);
            }
        }
        __syncthreads();

        // ======== odd phase: compute tile 2tt+1 from buf1 with bnxt ========
        if (tt < 15) {
            *reinterpret_cast<s8v*>(sd0) = pack8(a0lo, a0hi);        // tile 2tt+2 -> buf0
            if (tt < 14) {                                           // x tile 2tt+4 -> pair0
                a0lo = *reinterpret_cast<const f4*>(xsrc + (size_t)(2 * tt + 4) * 64);
                a0hi = *reinterpret_cast<const f4*>(xsrc + (size_t)(2 * tt + 4) * 64 + 4);
            }
            #pragma unroll
            for (int ks = 0; ks < 2; ++ks)                           // B tile 2tt+2 -> bcur
                #pragma unroll
                for (int ni = 0; ni < 6; ++ni)
                    bcur[ks][ni] = *reinterpret_cast<const s8v*>(
                        wtb + (size_t)ni * 32768 + (size_t)((2 * tt + 2) * 2 + ks) * 512);
        }
        #pragma unroll
        for (int ksub = 0; ksub < 2; ++ksub) {
            const char* cur = ALDS[1];
            s8v a0 = *reinterpret_cast<const s8v*>(cur + (wm * 32 + l16) * 144 + (ksub * 4 + quad) * 16);
            s8v a1 = *reinterpret_cast<const s8v*>(cur + (wm * 32 + 16 + l16) * 144 + (ksub * 4 + quad) * 16);
            #pragma unroll
            for (int ni = 0; ni < 6; ++ni) {
                acc[0][ni] = __builtin_amdgcn_mfma_f32_16x16x32_bf16(a0, bnxt[ksub][ni], acc[0][ni], 0, 0, 0);
                acc[1][ni] = __builtin_amdgcn_mfma_f32_16x16x32_bf16(a1, bnxt[ksub][ni], acc[1][ni], 0, 0, 0);
            }
        }
        __syncthreads();
    }

    // ---- epilogue: RoPE + fragment-packed stores ----
    const float cfreq = -0.10381025296f;  // -log2(10000)/128
    const int tb  = M0 >> 11;             // batch
    const int tl  = M0 & 2047;            // t of first row (multiple of 64)
    unsigned short* qpB = qp + (size_t)tb * 262144;
    unsigned short* kpB = kp + (size_t)tb * 262144;
    unsigned short* vpB = vp + (size_t)tb * 262144;
    const int qt0 = (tl >> 5) + wm;       // q-tile (32 rows)
    const int kt0 = tl >> 6;              // k/v tile (64 rows)

    #pragma unroll
    for (int mi = 0; mi < 2; ++mi) {
        #pragma unroll
        for (int ni = 0; ni < 6; ++ni) {
            const int outcol = wn * 96 + ni * 16 + l16;     // 0..383
            const int mat = outcol >> 7;                    // uniform per (wn,ni)
            const int col = outcol & 127;
            float vv[4];
            #pragma unroll
            for (int r = 0; r < 4; ++r) {
                const int t = tl + wm * 32 + mi * 16 + quad * 4 + r;
                float v = acc[mi][ni][r];
                if (mat < 2) {
                    float other = __shfl_xor(v, 1, 64);
                    float freq  = exp2f(cfreq * (float)(col & ~1));
                    float ang   = (float)t * freq;
                    float sn = sinf(ang), cs = cosf(ang);
                    v = (col & 1) ? (other * sn + v * cs)
                                  : (v * cs - other * sn);
                }
                vv[r] = v;
            }
            if (mat == 0) {
                const int ks = col >> 5, qq = (col >> 3) & 3, e = col & 7;
                unsigned short* d = qpB + ((((size_t)qt0 * 2 + mi) * 4 + ks) * 64 + qq * 16 + quad * 4) * 8 + e;
                #pragma unroll
                for (int r = 0; r < 4; ++r) d[r * 8] = f2bf(vv[r]);
            } else if (mat == 1) {
                const int ks = col >> 5, qq = (col >> 3) & 3, e = col & 7;
                const int nt = wm * 2 + mi;
                unsigned short* d = kpB + ((((size_t)kt0 * 4 + nt) * 4 + ks) * 64 + qq * 16 + quad * 4) * 8 + e;
                #pragma unroll
                for (int r = 0; r < 4; ++r) d[r * 8] = f2bf(vv[r]);
            } else {
                const int dt  = col >> 4;                    // l16v == l16
                const int ks2 = wm;
                const int qv  = mi * 2 + (quad >> 1);
                const int e4  = (quad & 1) * 4;
                unsigned short* d = vpB + ((((size_t)kt0 * 2 + ks2) * 8 + dt) * 64 + qv * 16 + l16) * 8 + e4;
                s4v pk;
                #pragma unroll
                for (int r = 0; r < 4; ++r) pk[r] = (short)f2bf(vv[r]);
                *reinterpret_cast<s4v*>(d) = pk;
            }
        }
    }
}

// ---------------------------------------------------------------------------
// Kernel 2: flash attention (causal). EXACT R5 body (52 µs verified) with ONE
// change: causal LOAD-BALANCE remap. Workload nkt = qt/2+1 varies 1..32; under
// round-robin dispatch the two co-resident blocks per CU are (bx,by),(bx,by+4)
// — same qt, so heavy CUs got 2x-heavy (makespan ~2x heaviest). Flipping the
// q-tile map for batches 4-7 makes co-resident pairs sum to ~constant work.
// Bijective per batch -> correctness unaffected regardless of dispatch model.
// ---------------------------------------------------------------------------
__global__ __launch_bounds__(256, 2) void attn_k(
    const unsigned short* __restrict__ qp, const unsigned short* __restrict__ kp,
    const unsigned short* __restrict__ vp, float* __restrict__ out)
{
    __shared__ unsigned short P[4][32 * 64];   // 16 KB, per-wave, swizzled
    __shared__ float Os[4][32][64];            // 32 KB (one half of d per pass)
    __shared__ float Ms[4][32], Ls[4][32], Lt[32];

    const int wave = threadIdx.x >> 6;
    const int lane = threadIdx.x & 63;
    const int quad = lane >> 4, l16 = lane & 15;
    const int b  = blockIdx.y;
    const int qt = (b & 4) ? (63 - blockIdx.x) : blockIdx.x;   // load-balance remap
    const int qrow0 = qt * 32;
    const unsigned short* Qp = qp + (size_t)b * 262144;
    const unsigned short* Kp = kp + (size_t)b * 262144;
    const unsigned short* Vp = vp + (size_t)b * 262144;

    s8v qf[2][4];
    #pragma unroll
    for (int mi = 0; mi < 2; ++mi)
        #pragma unroll
        for (int ks = 0; ks < 4; ++ks)
            qf[mi][ks] = *reinterpret_cast<const s8v*>(
                Qp + ((((size_t)qt * 2 + mi) * 4 + ks) * 64 + lane) * 8);

    float m[2][4], ls[2][4];
    f4 o[2][8];
    #pragma unroll
    for (int mi = 0; mi < 2; ++mi) {
        #pragma unroll
        for (int r = 0; r < 4; ++r) { m[mi][r] = -INFINITY; ls[mi][r] = 0.f; }
        #pragma unroll
        for (int dt = 0; dt < 8; ++dt) o[mi][dt] = (f4){0.f, 0.f, 0.f, 0.f};
    }

    const int nkt = (qrow0 >> 6) + 1;        // works for qrow0 = 0/32 mod 64
    const float scale2 = 0.1275166948f;      // (1/sqrt(128)) * log2(e)

    for (int kt = wave; kt < nkt; kt += 4) {
        const int kbase = kt * 64;
        const bool domask = (kt == nkt - 1);
        const unsigned short* Kt = Kp + (size_t)kt * 8192;   // [nt][ks][lane][8]
        const unsigned short* Vt = Vp + (size_t)kt * 8192;   // [ks2][dt][lane][8]

        // S = Q K^T
        f4 s[2][4];
        #pragma unroll
        for (int nt = 0; nt < 4; ++nt) {
            f4 a0 = (f4){0.f, 0.f, 0.f, 0.f}, a1 = a0;
            #pragma unroll
            for (int ks = 0; ks < 4; ++ks) {
                s8v kf = *reinterpret_cast<const s8v*>(Kt + (((nt * 4 + ks) * 64) + lane) * 8);
                a0 = __builtin_amdgcn_mfma_f32_16x16x32_bf16(qf[0][ks], kf, a0, 0, 0, 0);
                a1 = __builtin_amdgcn_mfma_f32_16x16x32_bf16(qf[1][ks], kf, a1, 0, 0, 0);
            }
            s[0][nt] = a0; s[1][nt] = a1;
        }

        // tile max (log2 domain)
        float tmx[2][4];
        #pragma unroll
        for (int mi = 0; mi < 2; ++mi) {
            #pragma unroll
            for (int r = 0; r < 4; ++r) {
                const int trow = qrow0 + mi * 16 + quad * 4 + r;
                #pragma unroll
                for (int nt = 0; nt < 4; ++nt) {
                    float sv = s[mi][nt][r] * scale2;
                    if (domask && (kbase + nt * 16 + l16 > trow)) sv = -INFINITY;
                    s[mi][nt][r] = sv;
                }
                float tm = fmaxf(fmaxf(s[mi][0][r], s[mi][1][r]),
                                 fmaxf(s[mi][2][r], s[mi][3][r]));
                #pragma unroll
                for (int off = 1; off < 16; off <<= 1)
                    tm = fmaxf(tm, __shfl_xor(tm, off, 64));
                tmx[mi][r] = tm;
            }
        }

        // defer-max: only rescale when some row's max grew by > 8 (log2 units)
        bool grow = false;
        #pragma unroll
        for (int mi = 0; mi < 2; ++mi)
            #pragma unroll
            for (int r = 0; r < 4; ++r)
                grow = grow || (tmx[mi][r] > m[mi][r] + 8.0f);
        if (__any(grow)) {
            #pragma unroll
            for (int mi = 0; mi < 2; ++mi)
                #pragma unroll
                for (int r = 0; r < 4; ++r) {
                    const float mn = fmaxf(m[mi][r], tmx[mi][r]);
                    const float alpha = exp2f(m[mi][r] - mn);
                    m[mi][r] = mn;
                    ls[mi][r] *= alpha;
                    #pragma unroll
                    for (int dt = 0; dt < 8; ++dt) o[mi][dt][r] *= alpha;
                }
        }

        // P = exp2(S - m); per-lane partial row sums
        #pragma unroll
        for (int mi = 0; mi < 2; ++mi)
            #pragma unroll
            for (int r = 0; r < 4; ++r) {
                float rs = 0.f;
                #pragma unroll
                for (int nt = 0; nt < 4; ++nt) {
                    float p = exp2f(s[mi][nt][r] - m[mi][r]);
                    s[mi][nt][r] = p;
                    rs += p;
                }
                ls[mi][r] += rs;
            }

        // P (C layout) -> LDS, XOR-swizzled: pos = chunk ^ (row&7), chunk=8 shorts
        #pragma unroll
        for (int mi = 0; mi < 2; ++mi)
            #pragma unroll
            for (int nt = 0; nt < 4; ++nt)
                #pragma unroll
                for (int r = 0; r < 4; ++r) {
                    const int prow = mi * 16 + quad * 4 + r;
                    const int swz  = ((nt * 2 + (l16 >> 3)) ^ (prow & 7)) * 8 + (l16 & 7);
                    P[wave][prow * 64 + swz] = f2bf(s[mi][nt][r]);
                }

        // O += P @ V
        #pragma unroll
        for (int ks2 = 0; ks2 < 2; ++ks2) {
            s8v pa[2];
            #pragma unroll
            for (int mi = 0; mi < 2; ++mi) {
                const int prow = mi * 16 + l16;                  // prow&7 == l16&7
                const int pp = ((ks2 * 4 + quad) ^ (l16 & 7));
                pa[mi] = *reinterpret_cast<const s8v*>(&P[wave][prow * 64 + pp * 8]);
            }
            #pragma unroll
            for (int dt = 0; dt < 8; ++dt) {
                s8v vf = *reinterpret_cast<const s8v*>(Vt + (((ks2 * 8 + dt) * 64) + lane) * 8);
                o[0][dt] = __builtin_amdgcn_mfma_f32_16x16x32_bf16(pa[0], vf, o[0][dt], 0, 0, 0);
                o[1][dt] = __builtin_amdgcn_mfma_f32_16x16x32_bf16(pa[1], vf, o[1][dt], 0, 0, 0);
            }
        }
    }

    // reduce per-lane lsum across the 16-lane row group
    #pragma unroll
    for (int mi = 0; mi < 2; ++mi)
        #pragma unroll
        for (int r = 0; r < 4; ++r) {
            float v = ls[mi][r];
            #pragma unroll
            for (int off = 1; off < 16; off <<= 1) v += __shfl_xor(v, off, 64);
            ls[mi][r] = v;
        }

    // ---- merge the 4 per-wave partials (m in log2 domain -> exp2) ----
    if (l16 == 0) {
        #pragma unroll
        for (int mi = 0; mi < 2; ++mi)
            #pragma unroll
            for (int r = 0; r < 4; ++r) {
                Ms[wave][mi * 16 + quad * 4 + r] = m[mi][r];
                Ls[wave][mi * 16 + quad * 4 + r] = ls[mi][r];
            }
    }
    __syncthreads();

    #pragma unroll
    for (int mi = 0; mi < 2; ++mi)
        #pragma unroll
        for (int r = 0; r < 4; ++r) {
            const int row = mi * 16 + quad * 4 + r;
            float M = fmaxf(fmaxf(Ms[0][row], Ms[1][row]), fmaxf(Ms[2][row], Ms[3][row]));
            float sc = exp2f(m[mi][r] - M);
            float lt = Ls[0][row] * exp2f(Ms[0][row] - M) + Ls[1][row] * exp2f(Ms[1][row] - M)
                     + Ls[2][row] * exp2f(Ms[2][row] - M) + Ls[3][row] * exp2f(Ms[3][row] - M);
            if (wave == 0 && l16 == 0) Lt[row] = lt;
            #pragma unroll
            for (int dt = 0; dt < 8; ++dt) o[mi][dt][r] *= sc;
        }

    const int rrow = threadIdx.x >> 3;          // 0..31
    const int cx   = (threadIdx.x & 7) * 8;     // 0..56
    #pragma unroll
    for (int h = 0; h < 2; ++h) {
        __syncthreads();
        #pragma unroll
        for (int mi = 0; mi < 2; ++mi)
            #pragma unroll
            for (int dtl = 0; dtl < 4; ++dtl)
                #pragma unroll
                for (int r = 0; r < 4; ++r)
                    Os[wave][mi * 16 + quad * 4 + r][dtl * 16 + l16] = o[mi][h * 4 + dtl][r];
        __syncthreads();
        f4 s0 = (f4){0.f, 0.f, 0.f, 0.f}, s1 = s0;
        #pragma unroll
        for (int w = 0; w < 4; ++w) {
            s0 += *reinterpret_cast<const f4*>(&Os[w][rrow][cx]);
            s1 += *reinterpret_cast<const f4*>(&Os[w][rrow][cx + 4]);
        }
        const float rl = 1.0f / Lt[rrow];
        float* dst = &out[((size_t)b * NT + qrow0 + rrow) * NH + h * 64 + cx];
        *reinterpret_cast<f4*>(dst)     = s0 * rl;
        *reinterpret_cast<f4*>(dst + 4) = s1 * rl;
    }
}

// ---------------------------------------------------------------------------
extern "C" void kernel_launch(void* const* d_in, const int* in_sizes, int n_in,
                              void* d_out, int out_size, void* d_ws, size_t ws_size,
                              hipStream_t stream) {
    const float* x  = (const float*)d_in[0];
    const float* Wk = (const float*)d_in[1];
    const float* Wq = (const float*)d_in[2];
    const float* Wv = (const float*)d_in[3];
    unsigned short* ws   = (unsigned short*)d_ws;
    unsigned short* wt   = ws;                      // 24 nb x 64 kb x 512 (packed W frags)
    unsigned short* qws  = ws  + 786432;            // 8 b x 64 qt x 2 x 4 x 64 x 8 (packed Q)
    unsigned short* kws  = qws + 2097152;           // 8 b x 32 kt x 4 x 4 x 64 x 8 (packed K)
    unsigned short* vtws = kws + 2097152;           // 8 b x 32 kt x 2 x 8 x 64 x 8 (packed V^T)
    float* outp = (float*)d_out;

    wtrans_k<<<dim3(32, 3), 256, 0, stream>>>(Wk, Wq, Wv, wt);
    proj_rope<<<dim3(256), 512, 0, stream>>>(x, wt, qws, kws, vtws);
    attn_k<<<dim3(64, 8), 256, 0, stream>>>(qws, kws, vtws, outp);
}

// Round 13
// 274.564 us; speedup vs baseline: 1.4593x; 1.0226x over previous
//
#include <hip/hip_runtime.h>

#define NB 8
#define NT 2048
#define NC 2048
#define NH 128

typedef short s8v __attribute__((ext_vector_type(8)));   // 8 bf16 (4 VGPRs) — MFMA A/B frag
typedef short s4v __attribute__((ext_vector_type(4)));   // 4 bf16 (8 B)
typedef float f4  __attribute__((ext_vector_type(4)));   // 4 fp32 — MFMA C/D frag

static __device__ __forceinline__ unsigned short f2bf(float f) {
    union { float f; unsigned int u; } v; v.f = f;
    unsigned int x = v.u;
    return (unsigned short)((x + 0x7FFFu + ((x >> 16) & 1u)) >> 16);  // RNE
}

static __device__ __forceinline__ s8v pack8(f4 lo, f4 hi) {          // fp32x8 -> bf16x8 (trunc)
    union { f4 f; unsigned int u[4]; } L, H; L.f = lo; H.f = hi;
    union { s8v s; unsigned int u[4]; } A;
    A.u[0] = __builtin_amdgcn_perm(L.u[1], L.u[0], 0x07060302u);
    A.u[1] = __builtin_amdgcn_perm(L.u[3], L.u[2], 0x07060302u);
    A.u[2] = __builtin_amdgcn_perm(H.u[1], H.u[0], 0x07060302u);
    A.u[3] = __builtin_amdgcn_perm(H.u[3], H.u[2], 0x07060302u);
    return A.s;
}

// ---------------------------------------------------------------------------
// Kernel 0: transpose + cast W[k][n] (2048x128 fp32) -> FRAGMENT-PACKED bf16:
// wt[nb][kb][quad*16+l16][8elems]  (nb = mat*8 + n/16, kb = k/32).
// grid (32 k-tiles of 64, 3 mats), block 256.  [verified R3-R12]
// ---------------------------------------------------------------------------
__global__ __launch_bounds__(256) void wtrans_k(
    const float* __restrict__ Wk, const float* __restrict__ Wq,
    const float* __restrict__ Wv, unsigned short* __restrict__ wt)
{
    __shared__ float Ls[64][129];                       // +1 pad: conflict-free transpose
    const int mat = blockIdx.y;
    const float* W = (mat == 0) ? Wq : (mat == 1) ? Wk : Wv;
    const int k0 = blockIdx.x * 64;
    const int t  = threadIdx.x;

    #pragma unroll
    for (int j = 0; j < 8; ++j) {                       // load 64x128 fp32, coalesced f4
        int flat = j * 1024 + t * 4;
        int k = flat >> 7, n = flat & 127;
        f4 v = *reinterpret_cast<const f4*>(W + (size_t)(k0 + k) * NH + n);
        Ls[k][n] = v[0]; Ls[k][n + 1] = v[1]; Ls[k][n + 2] = v[2]; Ls[k][n + 3] = v[3];
    }
    __syncthreads();

    const int n = t >> 1, half = t & 1;                 // thread: col n, one 32-k block
    unsigned short tmp[32];
    #pragma unroll
    for (int kk = 0; kk < 32; ++kk) tmp[kk] = f2bf(Ls[half * 32 + kk][n]);

    const int nb  = mat * 8 + (n >> 4);                 // 0..23
    const int l16 = n & 15;
    const int kbi = blockIdx.x * 2 + half;              // 0..63
    unsigned short* dst = wt + ((size_t)nb * 64 + kbi) * 512;
    #pragma unroll
    for (int v = 0; v < 4; ++v)                         // lane (l16, quad=v) slot
        *reinterpret_cast<s8v*>(dst + (v * 16 + l16) * 8) = *reinterpret_cast<s8v*>(tmp + v * 8);
}

// ---------------------------------------------------------------------------
// Kernel 1: FUSED projection (Q,K,V in one pass over x) + RoPE.
// EXACT R5/R12 structure — measured best (91 µs) across the R5-R10 sweep.
// block 512 (8 waves: 2m x 4n), M-tile 64, grid 256. A: global->reg (2 tiles
// early) -> pack bf16 -> ds_write; LDS dbuf 2 x 64rows x 144B. B: direct
// global->reg from fragment-packed wt. Outputs MFMA-FRAGMENT-PACKED.
// NEW vs R12: Q is PRE-SCALED by 1/sqrt(128)*log2(e) (fp32, commutes with
// the linear RoPE rotation) so attn's per-iter scale-mul disappears.
// ---------------------------------------------------------------------------
__global__ __launch_bounds__(512) void proj_rope(
    const float* __restrict__ x, const unsigned short* __restrict__ wt,
    unsigned short* __restrict__ qp, unsigned short* __restrict__ kp,
    unsigned short* __restrict__ vp)
{
    __shared__ char ALDS[2][9216];                       // 64 rows x 144B, dbuf

    const int tid  = threadIdx.x;
    const int wave = tid >> 6;
    const int lane = tid & 63;
    const int quad = lane >> 4, l16 = lane & 15;
    const int wm = wave >> 2, wn = wave & 3;             // 2m x 4n wave grid
    const int M0 = blockIdx.x * 64;

    // staging role: thread covers row srow (0..63), k-chunk sc (8 floats)
    const int srow = tid >> 3, sc = tid & 7;
    const float* xsrc = x + (size_t)(M0 + srow) * NC + sc * 8;
    char* sd0 = &ALDS[0][srow * 144 + sc * 16];
    char* sd1 = &ALDS[1][srow * 144 + sc * 16];

    const unsigned short* wtb = wt + (size_t)(wn * 6) * 32768 + lane * 8;

    f4 acc[2][6];
    #pragma unroll
    for (int mi = 0; mi < 2; ++mi)
        #pragma unroll
        for (int ni = 0; ni < 6; ++ni)
            acc[mi][ni] = (f4){0.f, 0.f, 0.f, 0.f};

    s8v bcur[2][6], bnxt[2][6];

    // prologue: x tiles 0,1 -> reg pairs; B tile 0 -> bcur; write tile0 -> buf0
    f4 a0lo = *reinterpret_cast<const f4*>(xsrc);
    f4 a0hi = *reinterpret_cast<const f4*>(xsrc + 4);
    f4 a1lo = *reinterpret_cast<const f4*>(xsrc + 64);
    f4 a1hi = *reinterpret_cast<const f4*>(xsrc + 68);
    #pragma unroll
    for (int ks = 0; ks < 2; ++ks)
        #pragma unroll
        for (int ni = 0; ni < 6; ++ni)
            bcur[ks][ni] = *reinterpret_cast<const s8v*>(wtb + (size_t)ni * 32768 + (size_t)ks * 512);
    *reinterpret_cast<s8v*>(sd0) = pack8(a0lo, a0hi);
    a0lo = *reinterpret_cast<const f4*>(xsrc + 128);     // tile 2
    a0hi = *reinterpret_cast<const f4*>(xsrc + 132);
    __syncthreads();

    for (int tt = 0; tt < 16; ++tt) {
        // ======== even phase: compute tile 2tt from buf0 with bcur ========
        *reinterpret_cast<s8v*>(sd1) = pack8(a1lo, a1hi);           // tile 2tt+1 -> buf1
        if (tt < 15) {                                               // x tile 2tt+3 -> pair1
            a1lo = *reinterpret_cast<const f4*>(xsrc + (size_t)(2 * tt + 3) * 64);
            a1hi = *reinterpret_cast<const f4*>(xsrc + (size_t)(2 * tt + 3) * 64 + 4);
        }
        #pragma unroll
        for (int ks = 0; ks < 2; ++ks)                               // B tile 2tt+1 -> bnxt
            #pragma unroll
            for (int ni = 0; ni < 6; ++ni)
                bnxt[ks][ni] = *reinterpret_cast<const s8v*>(
                    wtb + (size_t)ni * 32768 + (size_t)((2 * tt + 1) * 2 + ks) * 512);
        #pragma unroll
        for (int ksub = 0; ksub < 2; ++ksub) {
            const char* cur = ALDS[0];
            s8v a0 = *reinterpret_cast<const s8v*>(cur + (wm * 32 + l16) * 144 + (ksub * 4 + quad) * 16);
            s8v a1 = *reinterpret_cast<const s8v*>(cur + (wm * 32 + 16 + l16) * 144 + (ksub * 4 + quad) * 16);
            #pragma unroll
            for (int ni = 0; ni < 6; ++ni) {
                acc[0][ni] = __builtin_amdgcn_mfma_f32_16x16x32_bf16(a0, bcur[ksub][ni], acc[0][ni], 0, 0, 0);
                acc[1][ni] = __builtin_amdgcn_mfma_f32_16x16x32_bf16(a1, bcur[ksub][ni], acc[1][ni], 0, 0, 0);
            }
        }
        __syncthreads();

        // ======== odd phase: compute tile 2tt+1 from buf1 with bnxt ========
        if (tt < 15) {
            *reinterpret_cast<s8v*>(sd0) = pack8(a0lo, a0hi);        // tile 2tt+2 -> buf0
            if (tt < 14) {                                           // x tile 2tt+4 -> pair0
                a0lo = *reinterpret_cast<const f4*>(xsrc + (size_t)(2 * tt + 4) * 64);
                a0hi = *reinterpret_cast<const f4*>(xsrc + (size_t)(2 * tt + 4) * 64 + 4);
            }
            #pragma unroll
            for (int ks = 0; ks < 2; ++ks)                           // B tile 2tt+2 -> bcur
                #pragma unroll
                for (int ni = 0; ni < 6; ++ni)
                    bcur[ks][ni] = *reinterpret_cast<const s8v*>(
                        wtb + (size_t)ni * 32768 + (size_t)((2 * tt + 2) * 2 + ks) * 512);
        }
        #pragma unroll
        for (int ksub = 0; ksub < 2; ++ksub) {
            const char* cur = ALDS[1];
            s8v a0 = *reinterpret_cast<const s8v*>(cur + (wm * 32 + l16) * 144 + (ksub * 4 + quad) * 16);
            s8v a1 = *reinterpret_cast<const s8v*>(cur + (wm * 32 + 16 + l16) * 144 + (ksub * 4 + quad) * 16);
            #pragma unroll
            for (int ni = 0; ni < 6; ++ni) {
                acc[0][ni] = __builtin_amdgcn_mfma_f32_16x16x32_bf16(a0, bnxt[ksub][ni], acc[0][ni], 0, 0, 0);
                acc[1][ni] = __builtin_amdgcn_mfma_f32_16x16x32_bf16(a1, bnxt[ksub][ni], acc[1][ni], 0, 0, 0);
            }
        }
        __syncthreads();
    }

    // ---- epilogue: RoPE + fragment-packed stores ----
    const float cfreq  = -0.10381025296f;  // -log2(10000)/128
    const float qscale = 0.1275166948f;    // (1/sqrt(128)) * log2(e), folded into Q
    const int tb  = M0 >> 11;             // batch
    const int tl  = M0 & 2047;            // t of first row (multiple of 64)
    unsigned short* qpB = qp + (size_t)tb * 262144;
    unsigned short* kpB = kp + (size_t)tb * 262144;
    unsigned short* vpB = vp + (size_t)tb * 262144;
    const int qt0 = (tl >> 5) + wm;       // q-tile (32 rows)
    const int kt0 = tl >> 6;              // k/v tile (64 rows)

    #pragma unroll
    for (int mi = 0; mi < 2; ++mi) {
        #pragma unroll
        for (int ni = 0; ni < 6; ++ni) {
            const int outcol = wn * 96 + ni * 16 + l16;     // 0..383
            const int mat = outcol >> 7;                    // uniform per (wn,ni)
            const int col = outcol & 127;
            float vv[4];
            #pragma unroll
            for (int r = 0; r < 4; ++r) {
                const int t = tl + wm * 32 + mi * 16 + quad * 4 + r;
                float v = acc[mi][ni][r];
                if (mat < 2) {
                    float other = __shfl_xor(v, 1, 64);
                    float freq  = exp2f(cfreq * (float)(col & ~1));
                    float ang   = (float)t * freq;
                    float sn = sinf(ang), cs = cosf(ang);
                    v = (col & 1) ? (other * sn + v * cs)
                                  : (v * cs - other * sn);
                }
                vv[r] = v;
            }
            if (mat == 0) {
                const int ks = col >> 5, qq = (col >> 3) & 3, e = col & 7;
                unsigned short* d = qpB + ((((size_t)qt0 * 2 + mi) * 4 + ks) * 64 + qq * 16 + quad * 4) * 8 + e;
                #pragma unroll
                for (int r = 0; r < 4; ++r) d[r * 8] = f2bf(vv[r] * qscale);
            } else if (mat == 1) {
                const int ks = col >> 5, qq = (col >> 3) & 3, e = col & 7;
                const int nt = wm * 2 + mi;
                unsigned short* d = kpB + ((((size_t)kt0 * 4 + nt) * 4 + ks) * 64 + qq * 16 + quad * 4) * 8 + e;
                #pragma unroll
                for (int r = 0; r < 4; ++r) d[r * 8] = f2bf(vv[r]);
            } else {
                const int dt  = col >> 4;                    // l16v == l16
                const int ks2 = wm;
                const int qv  = mi * 2 + (quad >> 1);
                const int e4  = (quad & 1) * 4;
                unsigned short* d = vpB + ((((size_t)kt0 * 2 + ks2) * 8 + dt) * 64 + qv * 16 + l16) * 8 + e4;
                s4v pk;
                #pragma unroll
                for (int r = 0; r < 4; ++r) pk[r] = (short)f2bf(vv[r]);
                *reinterpret_cast<s4v*>(d) = pk;
            }
        }
    }
}

// ---------------------------------------------------------------------------
// Kernel 2: flash attention (causal). R12 body (load-balance remap kept) with
// two local changes: (a) Q pre-scaled in proj -> no per-iter scale mul;
// (b) LAZY tile-max: per-lane max + per-lane grow test only; the 16-lane
// shuffle reduce (32 ds-ops/iter) runs ONLY inside the rare __any(grow)
// branch. Trigger is exactly equivalent (any lane exceeding <=> row max
// exceeding); P stays bounded by 2^8. First iter (m=-inf) still triggers.
// ---------------------------------------------------------------------------
__global__ __launch_bounds__(256, 2) void attn_k(
    const unsigned short* __restrict__ qp, const unsigned short* __restrict__ kp,
    const unsigned short* __restrict__ vp, float* __restrict__ out)
{
    __shared__ unsigned short P[4][32 * 64];   // 16 KB, per-wave, swizzled
    __shared__ float Os[4][32][64];            // 32 KB (one half of d per pass)
    __shared__ float Ms[4][32], Ls[4][32], Lt[32];

    const int wave = threadIdx.x >> 6;
    const int lane = threadIdx.x & 63;
    const int quad = lane >> 4, l16 = lane & 15;
    const int b  = blockIdx.y;
    const int qt = (b & 4) ? (63 - blockIdx.x) : blockIdx.x;   // load-balance remap
    const int qrow0 = qt * 32;
    const unsigned short* Qp = qp + (size_t)b * 262144;
    const unsigned short* Kp = kp + (size_t)b * 262144;
    const unsigned short* Vp = vp + (size_t)b * 262144;

    s8v qf[2][4];
    #pragma unroll
    for (int mi = 0; mi < 2; ++mi)
        #pragma unroll
        for (int ks = 0; ks < 4; ++ks)
            qf[mi][ks] = *reinterpret_cast<const s8v*>(
                Qp + ((((size_t)qt * 2 + mi) * 4 + ks) * 64 + lane) * 8);

    float m[2][4], ls[2][4];
    f4 o[2][8];
    #pragma unroll
    for (int mi = 0; mi < 2; ++mi) {
        #pragma unroll
        for (int r = 0; r < 4; ++r) { m[mi][r] = -INFINITY; ls[mi][r] = 0.f; }
        #pragma unroll
        for (int dt = 0; dt < 8; ++dt) o[mi][dt] = (f4){0.f, 0.f, 0.f, 0.f};
    }

    const int nkt = (qrow0 >> 6) + 1;        // works for qrow0 = 0/32 mod 64

    for (int kt = wave; kt < nkt; kt += 4) {
        const int kbase = kt * 64;
        const bool domask = (kt == nkt - 1);
        const unsigned short* Kt = Kp + (size_t)kt * 8192;   // [nt][ks][lane][8]
        const unsigned short* Vt = Vp + (size_t)kt * 8192;   // [ks2][dt][lane][8]

        // S = Q K^T  (Q pre-scaled in proj: S already in log2-softmax domain)
        f4 s[2][4];
        #pragma unroll
        for (int nt = 0; nt < 4; ++nt) {
            f4 a0 = (f4){0.f, 0.f, 0.f, 0.f}, a1 = a0;
            #pragma unroll
            for (int ks = 0; ks < 4; ++ks) {
                s8v kf = *reinterpret_cast<const s8v*>(Kt + (((nt * 4 + ks) * 64) + lane) * 8);
                a0 = __builtin_amdgcn_mfma_f32_16x16x32_bf16(qf[0][ks], kf, a0, 0, 0, 0);
                a1 = __builtin_amdgcn_mfma_f32_16x16x32_bf16(qf[1][ks], kf, a1, 0, 0, 0);
            }
            s[0][nt] = a0; s[1][nt] = a1;
        }

        // mask + per-lane max (lazy: no cross-lane reduce on the fast path)
        float pmax[2][4];
        #pragma unroll
        for (int mi = 0; mi < 2; ++mi) {
            #pragma unroll
            for (int r = 0; r < 4; ++r) {
                const int trow = qrow0 + mi * 16 + quad * 4 + r;
                #pragma unroll
                for (int nt = 0; nt < 4; ++nt) {
                    float sv = s[mi][nt][r];
                    if (domask && (kbase + nt * 16 + l16 > trow)) sv = -INFINITY;
                    s[mi][nt][r] = sv;
                }
                pmax[mi][r] = fmaxf(fmaxf(s[mi][0][r], s[mi][1][r]),
                                    fmaxf(s[mi][2][r], s[mi][3][r]));
            }
        }

        // defer-max: rescale (with full 16-lane reduce) only when some lane's
        // max grew past m+8 (log2 units) — equivalent trigger to row-max test
        bool grow = false;
        #pragma unroll
        for (int mi = 0; mi < 2; ++mi)
            #pragma unroll
            for (int r = 0; r < 4; ++r)
                grow = grow || (pmax[mi][r] > m[mi][r] + 8.0f);
        if (__any(grow)) {
            #pragma unroll
            for (int mi = 0; mi < 2; ++mi)
                #pragma unroll
                for (int r = 0; r < 4; ++r) {
                    float tm = pmax[mi][r];
                    #pragma unroll
                    for (int off = 1; off < 16; off <<= 1)
                        tm = fmaxf(tm, __shfl_xor(tm, off, 64));
                    const float mn = fmaxf(m[mi][r], tm);
                    const float alpha = exp2f(m[mi][r] - mn);
                    m[mi][r] = mn;
                    ls[mi][r] *= alpha;
                    #pragma unroll
                    for (int dt = 0; dt < 8; ++dt) o[mi][dt][r] *= alpha;
                }
        }

        // P = exp2(S - m); per-lane partial row sums
        #pragma unroll
        for (int mi = 0; mi < 2; ++mi)
            #pragma unroll
            for (int r = 0; r < 4; ++r) {
                float rs = 0.f;
                #pragma unroll
                for (int nt = 0; nt < 4; ++nt) {
                    float p = exp2f(s[mi][nt][r] - m[mi][r]);
                    s[mi][nt][r] = p;
                    rs += p;
                }
                ls[mi][r] += rs;
            }

        // P (C layout) -> LDS, XOR-swizzled: pos = chunk ^ (row&7), chunk=8 shorts
        #pragma unroll
        for (int mi = 0; mi < 2; ++mi)
            #pragma unroll
            for (int nt = 0; nt < 4; ++nt)
                #pragma unroll
                for (int r = 0; r < 4; ++r) {
                    const int prow = mi * 16 + quad * 4 + r;
                    const int swz  = ((nt * 2 + (l16 >> 3)) ^ (prow & 7)) * 8 + (l16 & 7);
                    P[wave][prow * 64 + swz] = f2bf(s[mi][nt][r]);
                }

        // O += P @ V
        #pragma unroll
        for (int ks2 = 0; ks2 < 2; ++ks2) {
            s8v pa[2];
            #pragma unroll
            for (int mi = 0; mi < 2; ++mi) {
                const int prow = mi * 16 + l16;                  // prow&7 == l16&7
                const int pp = ((ks2 * 4 + quad) ^ (l16 & 7));
                pa[mi] = *reinterpret_cast<const s8v*>(&P[wave][prow * 64 + pp * 8]);
            }
            #pragma unroll
            for (int dt = 0; dt < 8; ++dt) {
                s8v vf = *reinterpret_cast<const s8v*>(Vt + (((ks2 * 8 + dt) * 64) + lane) * 8);
                o[0][dt] = __builtin_amdgcn_mfma_f32_16x16x32_bf16(pa[0], vf, o[0][dt], 0, 0, 0);
                o[1][dt] = __builtin_amdgcn_mfma_f32_16x16x32_bf16(pa[1], vf, o[1][dt], 0, 0, 0);
            }
        }
    }

    // reduce per-lane lsum across the 16-lane row group
    #pragma unroll
    for (int mi = 0; mi < 2; ++mi)
        #pragma unroll
        for (int r = 0; r < 4; ++r) {
            float v = ls[mi][r];
            #pragma unroll
            for (int off = 1; off < 16; off <<= 1) v += __shfl_xor(v, off, 64);
            ls[mi][r] = v;
        }

    // ---- merge the 4 per-wave partials (m in log2 domain -> exp2) ----
    if (l16 == 0) {
        #pragma unroll
        for (int mi = 0; mi < 2; ++mi)
            #pragma unroll
            for (int r = 0; r < 4; ++r) {
                Ms[wave][mi * 16 + quad * 4 + r] = m[mi][r];
                Ls[wave][mi * 16 + quad * 4 + r] = ls[mi][r];
            }
    }
    __syncthreads();

    #pragma unroll
    for (int mi = 0; mi < 2; ++mi)
        #pragma unroll
        for (int r = 0; r < 4; ++r) {
            const int row = mi * 16 + quad * 4 + r;
            float M = fmaxf(fmaxf(Ms[0][row], Ms[1][row]), fmaxf(Ms[2][row], Ms[3][row]));
            float sc = exp2f(m[mi][r] - M);
            float lt = Ls[0][row] * exp2f(Ms[0][row] - M) + Ls[1][row] * exp2f(Ms[1][row] - M)
                     + Ls[2][row] * exp2f(Ms[2][row] - M) + Ls[3][row] * exp2f(Ms[3][row] - M);
            if (wave == 0 && l16 == 0) Lt[row] = lt;
            #pragma unroll
            for (int dt = 0; dt < 8; ++dt) o[mi][dt][r] *= sc;
        }

    const int rrow = threadIdx.x >> 3;          // 0..31
    const int cx   = (threadIdx.x & 7) * 8;     // 0..56
    #pragma unroll
    for (int h = 0; h < 2; ++h) {
        __syncthreads();
        #pragma unroll
        for (int mi = 0; mi < 2; ++mi)
            #pragma unroll
            for (int dtl = 0; dtl < 4; ++dtl)
                #pragma unroll
                for (int r = 0; r < 4; ++r)
                    Os[wave][mi * 16 + quad * 4 + r][dtl * 16 + l16] = o[mi][h * 4 + dtl][r];
        __syncthreads();
        f4 s0 = (f4){0.f, 0.f, 0.f, 0.f}, s1 = s0;
        #pragma unroll
        for (int w = 0; w < 4; ++w) {
            s0 += *reinterpret_cast<const f4*>(&Os[w][rrow][cx]);
            s1 += *reinterpret_cast<const f4*>(&Os[w][rrow][cx + 4]);
        }
        const float rl = 1.0f / Lt[rrow];
        float* dst = &out[((size_t)b * NT + qrow0 + rrow) * NH + h * 64 + cx];
        *reinterpret_cast<f4*>(dst)     = s0 * rl;
        *reinterpret_cast<f4*>(dst + 4) = s1 * rl;
    }
}

// ---------------------------------------------------------------------------
extern "C" void kernel_launch(void* const* d_in, const int* in_sizes, int n_in,
                              void* d_out, int out_size, void* d_ws, size_t ws_size,
                              hipStream_t stream) {
    const float* x  = (const float*)d_in[0];
    const float* Wk = (const float*)d_in[1];
    const float* Wq = (const float*)d_in[2];
    const float* Wv = (const float*)d_in[3];
    unsigned short* ws   = (unsigned short*)d_ws;
    unsigned short* wt   = ws;                      // 24 nb x 64 kb x 512 (packed W frags)
    unsigned short* qws  = ws  + 786432;            // 8 b x 64 qt x 2 x 4 x 64 x 8 (packed Q)
    unsigned short* kws  = qws + 2097152;           // 8 b x 32 kt x 4 x 4 x 64 x 8 (packed K)
    unsigned short* vtws = kws + 2097152;           // 8 b x 32 kt x 2 x 8 x 64 x 8 (packed V^T)
    float* outp = (float*)d_out;

    wtrans_k<<<dim3(32, 3), 256, 0, stream>>>(Wk, Wq, Wv, wt);
    proj_rope<<<dim3(256), 512, 0, stream>>>(x, wt, qws, kws, vtws);
    attn_k<<<dim3(64, 8), 256, 0, stream>>>(qws, kws, vtws, outp);
}